// Round 3
// baseline (533.263 us; speedup 1.0000x reference)
//
#include <hip/hip_runtime.h>

#define H 1024
#define E 64
#define BT 64      // tokens per block
#define CK 32      // k-columns per s-half per iteration
#define NIT 16     // 512 / CK iterations

// W-via-SGPR MoE gate.
// Block = 256 threads: tid = s*128 + h*64 + tt.
//   tt = token (64/block), h = expert half (32 experts), s = K half (512 k).
//   h,s are WAVE-UNIFORM (waves 0,1,2,3 = (s,h) 00,01,10,11) -> W addresses
//   are uniform -> compiler emits s_load_dwordx16; v_fmac takes the SGPR
//   operand directly. LDS feeds only x (read ONCE per thread, not per
//   expert): LDS bytes/FMA drops ~30x vs the R2 tile kernel, which was
//   LDS-return-BW bound (2 B/FMA vs ~85-128 B/cyc/CU ceiling -> 100 us).
// VALU floor: 2*T*E*H / 157.3 TF = 27.3 us.
__global__ __launch_bounds__(256) void moe_gate_kernel(
    const float* __restrict__ x, const float* __restrict__ W,
    float* __restrict__ out, int T) {
  __shared__ float xs[BT][2 * CK + 4];  // [tok][64 k: cols 0-31 s0, 32-63 s1]
  __shared__ float ls[BT][E + 1];       // final logits, stride 65 (conflict-free)

  const int tid = threadIdx.x;
  const int tt  = tid & 63;
  const int s   = __builtin_amdgcn_readfirstlane(tid >> 7);
  const int h   = __builtin_amdgcn_readfirstlane((tid >> 6) & 1);
  const int t0  = blockIdx.x * BT;

  float acc[32];
#pragma unroll
  for (int e = 0; e < 32; ++e) acc[e] = 0.f;

  // wave-uniform W base: expert rows [32h, 32h+32), k offset 512s
  const float* wbase = W + (size_t)(h * 32) * H + s * 512;
  const int sb = s * CK;  // this wave's column window in xs

#pragma unroll 1
  for (int it = 0; it < NIT; ++it) {
    // Stage 64 tok x 64 k (both s-windows): 4 float4 per thread, coalesced
    // (16 lanes cover one 256 B row segment).
#pragma unroll
    for (int l = 0; l < 4; ++l) {
      int id  = tid + l * 256;
      int row = id >> 4;        // 0..63
      int c4  = id & 15;        // f4 column
      int kc  = c4 << 2;        // 0..60
      int kg  = (kc < CK) ? (it * CK + kc) : (512 + it * CK + (kc - CK));
      *(float4*)&xs[row][kc] = *(const float4*)&x[(size_t)(t0 + row) * H + kg];
    }
    __syncthreads();

    // x fragment: this thread's 32 k-values, read ONCE into registers.
    float xf[32];
#pragma unroll
    for (int j4 = 0; j4 < 8; ++j4) {
      float4 v = *(const float4*)&xs[tt][sb + (j4 << 2)];
      xf[j4 * 4 + 0] = v.x; xf[j4 * 4 + 1] = v.y;
      xf[j4 * 4 + 2] = v.z; xf[j4 * 4 + 3] = v.w;
    }
    // Barrier here (not after fmacs): xs is free as soon as all waves hold
    // xf, so next iter's staging overlaps the tail of other waves' fmacs.
    __syncthreads();

    const float* wit = wbase + it * CK;
#pragma unroll
    for (int ee = 0; ee < 32; ++ee) {
      const float* wr = wit + (size_t)ee * H;  // wave-uniform -> s_load
#pragma unroll
      for (int j = 0; j < CK; ++j)
        acc[ee] += xf[j] * wr[j];              // v_fmac_f32 vgpr, sgpr, vgpr
    }
  }

  // Reduce the two K-halves into ls, then top-2 epilogue.
  if (s == 1) {
#pragma unroll
    for (int e = 0; e < 32; ++e) ls[tt][h * 32 + e] = acc[e];
  }
  __syncthreads();
  if (s == 0) {
#pragma unroll
    for (int e = 0; e < 32; ++e) ls[tt][h * 32 + e] += acc[e];
  }
  __syncthreads();

  // One lane per token: top-2 of logits == top-2 of softmax (monotonic);
  // tie-break lower index first (matches jax.lax.top_k). Same epilogue as
  // the R1/R2 kernels that passed with absmax 0.
  if (tid < BT) {
    const int tk = tid;
    float m1 = -1e30f, m2 = -1e30f;
    int i1 = 0, i2 = 0;
#pragma unroll
    for (int e = 0; e < E; ++e) {
      float v = ls[tk][e];
      if (v > m1) {
        m2 = m1; i2 = i1;
        m1 = v;  i1 = e;
      } else if (v > m2) {
        m2 = v; i2 = e;
      }
    }
    float sden = 0.f;
#pragma unroll
    for (int e = 0; e < E; ++e) sden += expf(ls[tk][e] - m1);
    float p1 = 1.f / sden;            // exp(m1-m1)/sden
    float p2 = expf(m2 - m1) / sden;
    // second softmax over [p1, p2] (p1 >= p2 so exponent <= 0: stable)
    float e12 = expf(p2 - p1);
    float s1 = 1.f / (1.f + e12);
    float s2 = e12 * s1;

    size_t t = (size_t)(t0 + tk);
    out[t * 2 + 0] = s1;
    out[t * 2 + 1] = s2;
    float* idxo = out + (size_t)2 * T;
    idxo[t * 2 + 0] = (float)i1;
    idxo[t * 2 + 1] = (float)i2;
  }

  // trailing scalar output: zeros(())
  if (blockIdx.x == 0 && tid == 0) out[(size_t)4 * T] = 0.f;
}

extern "C" void kernel_launch(void* const* d_in, const int* in_sizes, int n_in,
                              void* d_out, int out_size, void* d_ws, size_t ws_size,
                              hipStream_t stream) {
  const float* x = (const float*)d_in[0];
  const float* W = (const float*)d_in[1];
  float* out = (float*)d_out;
  const int T = in_sizes[0] / H;  // 32768 tokens
  dim3 grid(T / BT), block(256);
  hipLaunchKernelGGL(moe_gate_kernel, grid, block, 0, stream, x, W, out, T);
}

// Round 4
// 251.065 us; speedup vs baseline: 2.1240x; 2.1240x over previous
//
#include <hip/hip_runtime.h>

#define H 1024
#define E 64
#define BT 64
#define BK 64

// Split-K-in-block MoE gate (R2 structure x2 occupancy + register prefetch).
// 512 threads = 2 k-halves (h = tid>>8) x 256. Each half runs the proven R2
// tile: 64 tok x 64 exp, 4x4 per thread, K=512 in 8 chunks of 64.
//   - R3 lesson: global uniform loads do NOT scalarize (stores+barriers kill
//     the invariance proof) -> W stays on the LDS path (R2's, which measured
//     conflict-free after the XOR swizzle).
//   - R2 lesson: 100 us was ds_read->fmac LATENCY at 2 waves/SIMD, not LDS
//     BW. Fix: 4 waves/SIMD (split-K) + explicit 1-step fragment prefetch
//     (64 fmacs = 128 cyc cover the ~120 cyc ds_read latency).
// LDS 69.7 KB -> 2 blocks/CU -> grid 512 = exactly resident, no tail.
__global__ __launch_bounds__(512) void moe_gate_kernel(
    const float* __restrict__ x, const float* __restrict__ W,
    float* __restrict__ out, int T) {
  __shared__ float xs[2][BT][BK + 4];
  __shared__ float ws[2][E][BK + 4];
  // epilogue logits overlay xs (dead after final sync); 16.6 KB < 34.8 KB
  float(*ls)[E + 1] = (float(*)[E + 1])xs;

  const int tid = threadIdx.x;
  const int h   = tid >> 8;      // k-half: 0 -> k[0,512), 1 -> k[512,1024)
  const int t   = tid & 255;
  const int tx  = t & 15;        // expert group
  const int ty  = t >> 4;        // token group (wave = 4 consecutive ty)
  const int t0  = blockIdx.x * BT;

  float acc[4][4];
#pragma unroll
  for (int r = 0; r < 4; ++r)
#pragma unroll
    for (int c = 0; c < 4; ++c) acc[r][c] = 0.f;

  const int kb = h * 512;  // this half's k-base

#pragma unroll 1
  for (int it = 0; it < 8; ++it) {
    const int k0 = kb + it * BK;
    // Stage this half's x-tile and W-tile [64 x 64]: 4 float4/thread,
    // coalesced (16 lanes cover one 256 B row segment).
#pragma unroll
    for (int l = 0; l < 4; ++l) {
      int id  = t + l * 256;     // 0..1023 f4 slots
      int row = id >> 4;         // 0..63
      int c4  = id & 15;
      int kc  = c4 << 2;
      *(float4*)&xs[h][row][kc] =
          *(const float4*)&x[(size_t)(t0 + row) * H + k0 + kc];
      int wc = c4 ^ (row >> 2);  // XOR swizzle (R2: kills 8-way b-conflicts)
      *(float4*)&ws[h][row][wc << 2] =
          *(const float4*)&W[(size_t)row * H + k0 + kc];
    }
    __syncthreads();

    const float(*xsh)[BK + 4] = xs[h];
    const float(*wsh)[BK + 4] = ws[h];

    // Inner 16 steps with explicit 1-step register prefetch.
    float4 a0[4], b0[4];
#pragma unroll
    for (int r = 0; r < 4; ++r) a0[r] = *(const float4*)&xsh[ty * 4 + r][0];
#pragma unroll
    for (int c = 0; c < 4; ++c)
      b0[c] = *(const float4*)&wsh[tx * 4 + c][(0 ^ tx) << 2];

#pragma unroll
    for (int kkf = 0; kkf < 16; ++kkf) {
      float4 a1[4], b1[4];
      if (kkf < 15) {
#pragma unroll
        for (int r = 0; r < 4; ++r)
          a1[r] = *(const float4*)&xsh[ty * 4 + r][(kkf + 1) << 2];
#pragma unroll
        for (int c = 0; c < 4; ++c)
          b1[c] = *(const float4*)&wsh[tx * 4 + c][((kkf + 1) ^ tx) << 2];
      }
#pragma unroll
      for (int r = 0; r < 4; ++r)
#pragma unroll
        for (int c = 0; c < 4; ++c) {
          acc[r][c] += a0[r].x * b0[c].x;
          acc[r][c] += a0[r].y * b0[c].y;
          acc[r][c] += a0[r].z * b0[c].z;
          acc[r][c] += a0[r].w * b0[c].w;
        }
      if (kkf < 15) {
#pragma unroll
        for (int r = 0; r < 4; ++r) a0[r] = a1[r];
#pragma unroll
        for (int c = 0; c < 4; ++c) b0[c] = b1[c];
      }
    }
    __syncthreads();
  }

  // Cross-half reduction into ls (overlaying xs), then top-2 epilogue.
  if (h == 0) {
#pragma unroll
    for (int r = 0; r < 4; ++r)
#pragma unroll
      for (int c = 0; c < 4; ++c) ls[ty * 4 + r][tx * 4 + c] = acc[r][c];
  }
  __syncthreads();
  if (h == 1) {
#pragma unroll
    for (int r = 0; r < 4; ++r)
#pragma unroll
      for (int c = 0; c < 4; ++c) ls[ty * 4 + r][tx * 4 + c] += acc[r][c];
  }
  __syncthreads();

  // One lane per token: top-2 of logits == top-2 of softmax (monotonic);
  // tie-break lower index first (matches jax.lax.top_k). Epilogue identical
  // to the R1/R2 kernels that passed with absmax 0.
  if (tid < BT) {
    const int tk = tid;
    float m1 = -1e30f, m2 = -1e30f;
    int i1 = 0, i2 = 0;
#pragma unroll
    for (int e = 0; e < E; ++e) {
      float v = ls[tk][e];
      if (v > m1) {
        m2 = m1; i2 = i1;
        m1 = v;  i1 = e;
      } else if (v > m2) {
        m2 = v; i2 = e;
      }
    }
    float sden = 0.f;
#pragma unroll
    for (int e = 0; e < E; ++e) sden += expf(ls[tk][e] - m1);
    float p1 = 1.f / sden;            // exp(m1-m1)/sden
    float p2 = expf(m2 - m1) / sden;
    // second softmax over [p1, p2] (p1 >= p2 so exponent <= 0: stable)
    float e12 = expf(p2 - p1);
    float s1 = 1.f / (1.f + e12);
    float s2 = e12 * s1;

    size_t tt = (size_t)(t0 + tk);
    out[tt * 2 + 0] = s1;
    out[tt * 2 + 1] = s2;
    float* idxo = out + (size_t)2 * T;
    idxo[tt * 2 + 0] = (float)i1;
    idxo[tt * 2 + 1] = (float)i2;
  }

  // trailing scalar output: zeros(())
  if (blockIdx.x == 0 && tid == 0) out[(size_t)4 * T] = 0.f;
}

extern "C" void kernel_launch(void* const* d_in, const int* in_sizes, int n_in,
                              void* d_out, int out_size, void* d_ws, size_t ws_size,
                              hipStream_t stream) {
  const float* x = (const float*)d_in[0];
  const float* W = (const float*)d_in[1];
  float* out = (float*)d_out;
  const int T = in_sizes[0] / H;  // 32768 tokens
  dim3 grid(T / BT), block(512);
  hipLaunchKernelGGL(moe_gate_kernel, grid, block, 0, stream, x, W, out, T);
}